// Round 5
// baseline (297.872 us; speedup 1.0000x reference)
//
#include <hip/hip_runtime.h>

typedef __bf16 bf16x8 __attribute__((ext_vector_type(8)));
typedef float f32x4 __attribute__((ext_vector_type(4)));
typedef float f32x16 __attribute__((ext_vector_type(16)));
typedef unsigned short ushort8 __attribute__((ext_vector_type(8)));
typedef unsigned int uint4v __attribute__((ext_vector_type(4)));

#define BATCH 8
#define SEQ 4096
#define DH 128
#define NELEM 4194304ull     // BATCH*SEQ*DH
#define KEYS_PS 1024         // keys per kh-stream (4 streams in-block)
#define STEPS 32             // KEYS_PS / 32
#define SC (0.08838834764831845f * 1.4426950408889634f)

// LDS map (u16 units), 16-wave block:
//   K[s][buf] : (s*2+buf)*4096          [0     .. 32767]  32 key-rows x 128 u16, src-swizzled byte^=(row&7)<<4
//   V[s][buf] : 32768 + (s*2+buf)*4096  [32768 .. 65535]  128 d-rows x 32 u16, slot^=(row>>1)&3
//   epilogue  : Abuf f32 @byte 0 (64KB), Bbuf f32 @byte 65536 (64KB), lb @byte 131072 (2KB)
#define OFF_VU16 32768
#define SMEM_MW 133120       // bytes; 1 block/CU (<=160KB)

__device__ __forceinline__ unsigned short f2bf(float x) {
    unsigned int u = __builtin_bit_cast(unsigned int, x);
    u = (u + 0x7FFFu + ((u >> 16) & 1u)) >> 16;
    return (unsigned short)u;
}
__device__ __forceinline__ ushort8 cvt8(const float* __restrict__ p) {
    f32x4 a = *(const f32x4*)p;
    f32x4 b = *(const f32x4*)(p + 4);
    ushort8 r;
    r[0] = f2bf(a[0]); r[1] = f2bf(a[1]); r[2] = f2bf(a[2]); r[3] = f2bf(a[3]);
    r[4] = f2bf(b[0]); r[5] = f2bf(b[1]); r[6] = f2bf(b[2]); r[7] = f2bf(b[3]);
    return r;
}
__device__ __forceinline__ bf16x8 ldb(const unsigned short* p) {
    return __builtin_bit_cast(bf16x8, *(const ushort8*)p);
}
__device__ __forceinline__ void gll16(const void* src, void* dst) {
    __builtin_amdgcn_global_load_lds((const __attribute__((address_space(1))) unsigned int*)src,
                                     (__attribute__((address_space(3))) unsigned int*)dst, 16, 0, 0);
}
__device__ __forceinline__ unsigned int cvtpk(float lo, float hi) {
    unsigned int r;
    asm("v_cvt_pk_bf16_f32 %0, %1, %2" : "=v"(r) : "v"(lo), "v"(hi));
    return r;
}
__device__ __forceinline__ bf16x8 frag4(unsigned int a, unsigned int b,
                                        unsigned int c, unsigned int d) {
    uint4v u; u[0] = a; u[1] = b; u[2] = c; u[3] = d;
    return __builtin_bit_cast(bf16x8, u);
}

// ---------------- merged prep kernel: K->bf16, V->bf16 transposed ----------------
__global__ __launch_bounds__(256) void prep_all(const float* __restrict__ Kg,
                                                const float* __restrict__ Vg,
                                                unsigned short* __restrict__ Kbf,
                                                unsigned short* __restrict__ Vtg) {
    __shared__ float T[32 * 36];
    if (blockIdx.x < 2048) {
        size_t i = ((size_t)blockIdx.x * 256 + threadIdx.x) * 8;
        *(ushort8*)(Kbf + i) = cvt8(Kg + i);
        return;
    }
    const int bid = blockIdx.x - 2048;
    const int b  = bid >> 9;
    const int kt = (bid >> 2) & 127;
    const int dt = bid & 3;
    const int tid = threadIdx.x;
    {
        int r = tid >> 3, c4 = (tid & 7) * 4;
        f32x4 v = *(const f32x4*)(Vg + ((size_t)b * SEQ + kt * 32 + r) * DH + dt * 32 + c4);
        *(f32x4*)(&T[r * 36 + c4]) = v;
    }
    __syncthreads();
    {
        int rd = tid >> 3, kc4 = (tid & 7) * 4;
        unsigned long long w = 0;
#pragma unroll
        for (int j = 0; j < 4; ++j)
            w |= (unsigned long long)f2bf(T[(kc4 + j) * 36 + rd]) << (16 * j);
        *(unsigned long long*)(Vtg + ((size_t)b * DH + dt * 32 + rd) * SEQ + kt * 32 + kc4) = w;
    }
}

// ==================================================================================
// 16-wave attention: 256 blocks (8b x 32qt), 1024 threads = 4 qw x 4 kh waves.
// Each kh-stream: 1024 keys, 32 steps of 32 keys, double-buffered K+V in LDS.
// Swapped-operand QK^T (lane-local q-row softmax), in-register P, LDS kh-merge.
// ==================================================================================
__global__ __launch_bounds__(1024, 4)
void attn_mw(const float* __restrict__ Qg, const float* __restrict__ Kg,
             const float* __restrict__ Vg,
             const unsigned short* __restrict__ Kbf,
             const unsigned short* __restrict__ Vtg,
             float* __restrict__ Og, int prep)
{
    extern __shared__ __align__(16) unsigned char smem[];
    unsigned short* sm16 = (unsigned short*)smem;

    const int tid  = threadIdx.x;
    const int wv   = tid >> 6;          // 0..15
    const int lane = tid & 63;
    const int l32  = lane & 31;
    const int h    = lane >> 5;
    const int qw   = wv & 3;            // q-chunk within block (32 q each)
    const int kh   = wv >> 2;           // key stream 0..3 (1024 keys each)

    const int b   = blockIdx.x & 7;     // batch == XCD slot
    const int qt5 = blockIdx.x >> 3;    // 0..31 (128 q-rows each)
    const size_t qbase = (size_t)b * SEQ + (size_t)qt5 * 128 + qw * 32;

    // Q as B-operand: B[k][n=q], n=l32 -> row qbase+l32 ; k = h*8+j per d-chunk c
    bf16x8 qf[8];
#pragma unroll
    for (int c = 0; c < 8; ++c)
        qf[c] = __builtin_bit_cast(bf16x8, cvt8(Qg + (qbase + l32) * DH + c * 16 + h * 8));

    f32x16 oacc[4];
#pragma unroll
    for (int dt = 0; dt < 4; ++dt)
#pragma unroll
        for (int r = 0; r < 16; ++r) oacc[dt][r] = 0.f;
    float lpA = 0.f, lpB = 0.f;
    const int swzK = (l32 & 7) << 4;

    // ---- staging role: wave wv stages half of one tile (4 x gll, 1KB each)
    // s = wv&3 (stream), part = wv>>2 : 0,1 -> K halves ; 2,3 -> V halves
    const int sgs  = wv & 3;
    const int part = wv >> 2;
    const unsigned char* srcp[4];
    long sstr;
    unsigned ldsb;                       // u16 base (buf=0)
    if (prep) {
        if (part < 2) {
            const unsigned short* Kb = Kbf + (size_t)b * SEQ * DH;
#pragma unroll
            for (int ch = 0; ch < 4; ++ch) {
                const int row  = part * 16 + ch * 4 + (lane >> 4);
                const int colb = ((lane & 15) << 4) ^ ((row & 7) << 4);
                srcp[ch] = (const unsigned char*)(Kb + (size_t)(sgs * KEYS_PS + row) * DH) + colb;
            }
            sstr = 32 * DH * 2;          // 8 KB per step
            ldsb = sgs * 8192 + part * 2048;
        } else {
            const unsigned short* Vb = Vtg + (size_t)b * DH * SEQ;
            const int hf = part - 2;
#pragma unroll
            for (int ch = 0; ch < 4; ++ch) {
                const int row  = hf * 64 + ch * 16 + (lane >> 2);
                const int slot = (lane & 3) ^ ((row >> 1) & 3);
                srcp[ch] = (const unsigned char*)(Vb + (size_t)row * SEQ + sgs * KEYS_PS + slot * 8);
            }
            sstr = 64;                   // 32 keys per step
            ldsb = OFF_VU16 + sgs * 8192 + hf * 2048;
        }
    }

#define STAGE(bufv)                                                      \
    {                                                                    \
        unsigned short* bse = sm16 + ldsb + (bufv) * 4096;               \
        _Pragma("unroll")                                                \
        for (int ch = 0; ch < 4; ++ch) {                                 \
            gll16(srcp[ch], bse + ch * 512);                             \
            srcp[ch] += sstr;                                            \
        }                                                                \
    }

    // fallback staging (ws too small): all 1024 threads, f32 loads + cvt, correctness only
#define STAGE_FB(tt)                                                                  \
    {                                                                                 \
        const int bufv = (tt) & 1;                                                    \
        {   int s2 = tid >> 8, r = (tid >> 3) & 31, cg = tid & 7;                     \
            int kb = s2 * KEYS_PS + (tt) * 32;                                        \
            const float* sp = Kg + ((size_t)b * SEQ + kb + r) * DH + cg * 16;         \
            ushort8 lo = cvt8(sp), hi = cvt8(sp + 8);                                 \
            unsigned char* kd = (unsigned char*)(sm16 + s2 * 8192 + bufv * 4096) + r * 256; \
            int sbb = cg * 32, mm = (r & 7) << 4;                                     \
            *(ushort8*)(kd + (sbb ^ mm))        = lo;                                 \
            *(ushort8*)(kd + ((sbb + 16) ^ mm)) = hi;                                 \
        }                                                                             \
        {   int s2 = tid >> 8, d = (tid >> 1) & 127, hf2 = tid & 1, sw = (d >> 1) & 3;\
            int kb = s2 * KEYS_PS + (tt) * 32;                                        \
            ushort8 a, c;                                                             \
            _Pragma("unroll")                                                         \
            for (int j = 0; j < 8; ++j) {                                             \
                a[j] = f2bf(Vg[((size_t)b * SEQ + kb + hf2 * 16 + j) * DH + d]);      \
                c[j] = f2bf(Vg[((size_t)b * SEQ + kb + hf2 * 16 + 8 + j) * DH + d]);  \
            }                                                                         \
            unsigned short* vd = sm16 + OFF_VU16 + s2 * 8192 + bufv * 4096 + d * 32;  \
            *(ushort8*)(vd + ((hf2 * 2    ) ^ sw) * 8) = a;                           \
            *(ushort8*)(vd + ((hf2 * 2 + 1) ^ sw) * 8) = c;                           \
        }                                                                             \
    }

    if (prep) { STAGE(0); }
    else      { STAGE_FB(0); }
    asm volatile("s_waitcnt vmcnt(0) lgkmcnt(0)" ::: "memory");
    __builtin_amdgcn_s_barrier();
    asm volatile("" ::: "memory");

    for (int t = 0; t < STEPS; ++t) {
        const int buf = t & 1;
        // issue-early: stage tile t+1 while computing tile t (loads in flight all phase)
        if (t < STEPS - 1) {
            if (prep) { STAGE(buf ^ 1); }
            else      { STAGE_FB(t + 1); }
        }

        const unsigned char*  Kbb = (const unsigned char*)(sm16 + kh * 8192 + buf * 4096);
        const unsigned short* Vt  = sm16 + OFF_VU16 + kh * 8192 + buf * 4096;

        // ---- S^T = K * Q^T : 32key x 32q, lane-local q-row (swapped operands)
        __builtin_amdgcn_s_setprio(1);
        f32x16 s;
#pragma unroll
        for (int r = 0; r < 16; ++r) s[r] = 0.f;
#pragma unroll
        for (int c = 0; c < 8; ++c) {
            bf16x8 kf = ldb((const unsigned short*)(Kbb + l32 * 256 + ((c * 32 + h * 16) ^ swzK)));
            s = __builtin_amdgcn_mfma_f32_32x32x16_bf16(kf, qf[c], s, 0, 0, 0);
        }
        __builtin_amdgcn_s_setprio(0);

        // ---- P = exp2(S*SC) in-register; pack bf16 pairs; half-swap into A-frags
        unsigned int w[8];
#pragma unroll
        for (int i = 0; i < 8; ++i) {
            float pa = exp2f(s[2 * i]     * SC);
            float pb = exp2f(s[2 * i + 1] * SC);
            lpA += pa; lpB += pb;
            w[i] = cvtpk(pa, pb);
        }
        unsigned int t0 = __shfl_xor(h ? w[0] : w[2], 32);
        unsigned int t1 = __shfl_xor(h ? w[1] : w[3], 32);
        unsigned int t2 = __shfl_xor(h ? w[4] : w[6], 32);
        unsigned int t3 = __shfl_xor(h ? w[5] : w[7], 32);
        bf16x8 pf0 = frag4(h ? t0 : w[0], h ? t1 : w[1], h ? w[2] : t0, h ? w[3] : t1);
        bf16x8 pf1 = frag4(h ? t2 : w[4], h ? t3 : w[5], h ? w[6] : t2, h ? w[7] : t3);

        // ---- O += P*V
        __builtin_amdgcn_s_setprio(1);
#pragma unroll
        for (int dt = 0; dt < 4; ++dt) {
            const int d  = dt * 32 + l32;
            const int sw = (d >> 1) & 3;
            bf16x8 v0 = ldb(Vt + d * 32 + ((h    ) ^ sw) * 8);
            bf16x8 v1 = ldb(Vt + d * 32 + ((2 + h) ^ sw) * 8);
            oacc[dt] = __builtin_amdgcn_mfma_f32_32x32x16_bf16(pf0, v0, oacc[dt], 0, 0, 0);
            oacc[dt] = __builtin_amdgcn_mfma_f32_32x32x16_bf16(pf1, v1, oacc[dt], 0, 0, 0);
        }
        __builtin_amdgcn_s_setprio(0);

        asm volatile("s_waitcnt vmcnt(0) lgkmcnt(0)" ::: "memory");   // own stage landed
        __builtin_amdgcn_s_barrier();                                  // tile t+1 visible
        asm volatile("" ::: "memory");
    }
#undef STAGE
#undef STAGE_FB

    // ---- 4-way kh merge in LDS (tree): kh2->A, kh3->B ; kh0+=A, kh1+=B ; kh1->A ; kh0 final
    float lp2 = lpA + lpB;
    lp2 += __shfl_xor(lp2, 32);          // q = qw*32 + l32, stream-kh denominator
    float* Abuf = (float*)sm16;                       // 64 KB: 128q x 128d
    float* Bbuf = (float*)(smem + 65536);             // 64 KB
    float* lb   = (float*)(smem + 131072);            // 512 f32
    if (h == 0) lb[kh * 128 + qw * 32 + l32] = lp2;
    __syncthreads();
    if (kh >= 2) {
        float* Wb = (kh == 2) ? Abuf : Bbuf;
#pragma unroll
        for (int dt = 0; dt < 4; ++dt)
#pragma unroll
            for (int r = 0; r < 16; ++r) {
                const int qr = (r & 3) + 8 * (r >> 2) + 4 * h;
                Wb[(qw * 32 + qr) * 128 + dt * 32 + l32] = oacc[dt][r];
            }
    }
    __syncthreads();
    if (kh < 2) {
        const float* Rb = (kh == 0) ? Abuf : Bbuf;
#pragma unroll
        for (int dt = 0; dt < 4; ++dt)
#pragma unroll
            for (int r = 0; r < 16; ++r) {
                const int qr = (r & 3) + 8 * (r >> 2) + 4 * h;
                oacc[dt][r] += Rb[(qw * 32 + qr) * 128 + dt * 32 + l32];
            }
    }
    __syncthreads();
    if (kh == 1) {
#pragma unroll
        for (int dt = 0; dt < 4; ++dt)
#pragma unroll
            for (int r = 0; r < 16; ++r) {
                const int qr = (r & 3) + 8 * (r >> 2) + 4 * h;
                Abuf[(qw * 32 + qr) * 128 + dt * 32 + l32] = oacc[dt][r];
            }
    }
    __syncthreads();
    if (kh == 0) {
        float invr[16];
#pragma unroll
        for (int r = 0; r < 16; ++r) {
            const int qr = (r & 3) + 8 * (r >> 2) + 4 * h;
            const int qi = qw * 32 + qr;
            invr[r] = 1.0f / (lb[qi] + lb[128 + qi] + lb[256 + qi] + lb[384 + qi]);
        }
#pragma unroll
        for (int dt = 0; dt < 4; ++dt)
#pragma unroll
            for (int r = 0; r < 16; ++r) {
                const int qr = (r & 3) + 8 * (r >> 2) + 4 * h;
                Og[(qbase + qr) * DH + dt * 32 + l32] =
                    (oacc[dt][r] + Abuf[(qw * 32 + qr) * 128 + dt * 32 + l32]) * invr[r];
            }
    }
}

extern "C" void kernel_launch(void* const* d_in, const int* in_sizes, int n_in,
                              void* d_out, int out_size, void* d_ws, size_t ws_size,
                              hipStream_t stream) {
    const float* Q = (const float*)d_in[0];
    const float* K = (const float*)d_in[1];
    const float* V = (const float*)d_in[2];
    float* O = (float*)d_out;

    const size_t prep_bytes = NELEM * 2 * 2;           // 16.8 MB: Kbf + Vtg
    const bool prep = (ws_size >= prep_bytes);
    unsigned short* Kbf = (unsigned short*)d_ws;
    unsigned short* Vtg = Kbf + NELEM;

    static int smem_cfged = 0;
    if (!smem_cfged) {
        (void)hipFuncSetAttribute((const void*)attn_mw,
                                  hipFuncAttributeMaxDynamicSharedMemorySize, SMEM_MW);
        smem_cfged = 1;
    }

    if (prep)
        prep_all<<<dim3(2048 + BATCH * 128 * 4), 256, 0, stream>>>(K, V, Kbf, Vtg);
    attn_mw<<<dim3(BATCH * 32), 1024, SMEM_MW, stream>>>(Q, K, V, Kbf, Vtg, O, prep ? 1 : 0);
}

// Round 6
// 191.007 us; speedup vs baseline: 1.5595x; 1.5595x over previous
//
#include <hip/hip_runtime.h>

typedef __bf16 bf16x8 __attribute__((ext_vector_type(8)));
typedef float f32x4 __attribute__((ext_vector_type(4)));
typedef float f32x16 __attribute__((ext_vector_type(16)));
typedef unsigned short ushort8 __attribute__((ext_vector_type(8)));
typedef unsigned int uint4v __attribute__((ext_vector_type(4)));

#define BATCH 8
#define SEQ 4096
#define DH 128
#define NELEM 4194304ull     // BATCH*SEQ*DH
#define KSPLIT 4
#define KEYS_PS 1024         // keys per split
#define STEPS 32             // KEYS_PS / 32
#define SC (0.08838834764831845f * 1.4426950408889634f)

// ---- legacy dynamic-LDS map (u16 units), proven R3 path ----
#define OFF_V 16384
#define SMEM_BYTES 75776

__device__ __forceinline__ unsigned short f2bf(float x) {
    unsigned int u = __builtin_bit_cast(unsigned int, x);
    u = (u + 0x7FFFu + ((u >> 16) & 1u)) >> 16;
    return (unsigned short)u;
}
__device__ __forceinline__ ushort8 cvt8(const float* __restrict__ p) {
    f32x4 a = *(const f32x4*)p;
    f32x4 b = *(const f32x4*)(p + 4);
    ushort8 r;
    r[0] = f2bf(a[0]); r[1] = f2bf(a[1]); r[2] = f2bf(a[2]); r[3] = f2bf(a[3]);
    r[4] = f2bf(b[0]); r[5] = f2bf(b[1]); r[6] = f2bf(b[2]); r[7] = f2bf(b[3]);
    return r;
}
__device__ __forceinline__ bf16x8 ldb(const unsigned short* p) {
    return __builtin_bit_cast(bf16x8, *(const ushort8*)p);
}
__device__ __forceinline__ void gll16(const void* src, void* dst) {
    __builtin_amdgcn_global_load_lds((const __attribute__((address_space(1))) unsigned int*)src,
                                     (__attribute__((address_space(3))) unsigned int*)dst, 16, 0, 0);
}
__device__ __forceinline__ unsigned int cvtpk(float lo, float hi) {
    unsigned int r;
    asm("v_cvt_pk_bf16_f32 %0, %1, %2" : "=v"(r) : "v"(lo), "v"(hi));
    return r;
}
__device__ __forceinline__ bf16x8 frag4(unsigned int a, unsigned int b,
                                        unsigned int c, unsigned int d) {
    uint4v u; u[0] = a; u[1] = b; u[2] = c; u[3] = d;
    return __builtin_bit_cast(bf16x8, u);
}

// ---------------- merged prep kernel: K->bf16, V->bf16 transposed ----------------
__global__ __launch_bounds__(256) void prep_all(const float* __restrict__ Kg,
                                                const float* __restrict__ Vg,
                                                unsigned short* __restrict__ Kbf,
                                                unsigned short* __restrict__ Vtg) {
    __shared__ float T[32 * 36];
    if (blockIdx.x < 2048) {
        size_t i = ((size_t)blockIdx.x * 256 + threadIdx.x) * 8;
        *(ushort8*)(Kbf + i) = cvt8(Kg + i);
        return;
    }
    const int bid = blockIdx.x - 2048;
    const int b  = bid >> 9;
    const int kt = (bid >> 2) & 127;
    const int dt = bid & 3;
    const int tid = threadIdx.x;
    {
        int r = tid >> 3, c4 = (tid & 7) * 4;
        f32x4 v = *(const f32x4*)(Vg + ((size_t)b * SEQ + kt * 32 + r) * DH + dt * 32 + c4);
        *(f32x4*)(&T[r * 36 + c4]) = v;
    }
    __syncthreads();
    {
        int rd = tid >> 3, kc4 = (tid & 7) * 4;
        unsigned long long w = 0;
#pragma unroll
        for (int j = 0; j < 4; ++j)
            w |= (unsigned long long)f2bf(T[(kc4 + j) * 36 + rd]) << (16 * j);
        *(unsigned long long*)(Vtg + ((size_t)b * DH + dt * 32 + rd) * SEQ + kt * 32 + kc4) = w;
    }
}

// ==================================================================================
// SPLIT-K PATH: 1024 blocks (8b x 32qt x 4ks), 4 waves x 32q, one 1024-key stream.
// LDS 32KB; __launch_bounds__(256,2) -> 128 VGPR (spill-free, R3-proven codegen);
// HW residency at 128 VGPR = 4 waves/SIMD -> 4 blocks/CU = 16 waves/CU.
// LDS map (u16): K[buf] at buf*4096 (32 rows x 256B, src-swizzled byte^=(row&7)<<4)
//                V[buf] at 8192+buf*4096 (128 rows x 64B, slot^=(row>>1)&3)
// ==================================================================================
__global__ __launch_bounds__(256, 2)
void attn_split(const float* __restrict__ Qg,
                const unsigned short* __restrict__ Kbf,
                const unsigned short* __restrict__ Vtg,
                float* __restrict__ Opart, float* __restrict__ Lpart)
{
    __shared__ __align__(16) unsigned short sm16[16384];   // 32 KB

    const int tid  = threadIdx.x;
    const int wv   = tid >> 6;
    const int lane = tid & 63;
    const int l32  = lane & 31;
    const int h    = lane >> 5;

    const int b  = blockIdx.x & 7;          // batch -> XCD slot (K/V L2 locality)
    const int rr = blockIdx.x >> 3;         // 0..127
    const int ks = rr & 3;
    const int qt = rr >> 2;                 // 0..31
    const int q0 = qt * 128 + wv * 32;
    const size_t qbase = (size_t)b * SEQ + q0;
    const int kb0 = ks * KEYS_PS;

    // Q as B-operand: B[k][n=q], n = l32 -> row qbase+l32 ; k = h*8+j per d-chunk c
    bf16x8 qf[8];
#pragma unroll
    for (int c = 0; c < 8; ++c)
        qf[c] = __builtin_bit_cast(bf16x8, cvt8(Qg + (qbase + l32) * DH + c * 16 + h * 8));

    f32x16 oacc[4];
#pragma unroll
    for (int dt = 0; dt < 4; ++dt)
#pragma unroll
        for (int r = 0; r < 16; ++r) oacc[dt][r] = 0.f;
    float lpA = 0.f, lpB = 0.f;
    const int swzK = (l32 & 7) << 4;

    // persistent staging source pointers (role by wave: wv<2 -> K, else V)
    const unsigned char* srcp[4];
    long sstr;
    if (wv < 2) {
        const unsigned short* Kb = Kbf + (size_t)b * SEQ * DH;
#pragma unroll
        for (int ch = 0; ch < 4; ++ch) {
            const int row  = wv * 16 + ch * 4 + (lane >> 4);
            const int colb = ((lane & 15) << 4) ^ ((row & 7) << 4);
            srcp[ch] = (const unsigned char*)(Kb + (size_t)(kb0 + row) * DH) + colb;
        }
        sstr = 32 * DH * 2;        // 8192 B per step
    } else {
        const unsigned short* Vb = Vtg + (size_t)b * DH * SEQ;
#pragma unroll
        for (int ch = 0; ch < 4; ++ch) {
            const int row  = (wv - 2) * 64 + ch * 16 + (lane >> 2);
            const int slot = (lane & 3) ^ ((row >> 1) & 3);
            srcp[ch] = (const unsigned char*)(Vb + (size_t)row * SEQ + kb0 + slot * 8);
        }
        sstr = 64;                 // 32 keys * 2 B per step
    }

    // stage one tile quarter (4 x gll, 1KB each) into buf; advance sources
#define STAGE(bufv)                                                                 \
    {                                                                               \
        unsigned short* bse = (wv < 2)                                              \
            ? sm16 + (bufv) * 4096 + wv * 2048                                      \
            : sm16 + 8192 + (bufv) * 4096 + (wv - 2) * 2048;                        \
        _Pragma("unroll")                                                           \
        for (int ch = 0; ch < 4; ++ch) {                                            \
            gll16(srcp[ch], bse + ch * 512);                                        \
            srcp[ch] += sstr;                                                       \
        }                                                                           \
    }

    STAGE(0);
    asm volatile("s_waitcnt vmcnt(0)" ::: "memory");
    __builtin_amdgcn_s_barrier();
    asm volatile("" ::: "memory");

    for (int t = 0; t < STEPS; ++t) {
        const int buf = t & 1;
        if (t < STEPS - 1) STAGE(buf ^ 1);      // issue-early; wait late (full compute phase in flight)

        const unsigned char*  Kbb = (const unsigned char*)(sm16 + buf * 4096);
        const unsigned short* Vt  = sm16 + 8192 + buf * 4096;

        // ---- S^T = K * Q^T : 32key x 32q, lane-local q-row (swapped operands)
        __builtin_amdgcn_s_setprio(1);
        f32x16 s;
#pragma unroll
        for (int r = 0; r < 16; ++r) s[r] = 0.f;
#pragma unroll
        for (int c = 0; c < 8; ++c) {
            bf16x8 kf = ldb((const unsigned short*)(Kbb + l32 * 256 + ((c * 32 + h * 16) ^ swzK)));
            s = __builtin_amdgcn_mfma_f32_32x32x16_bf16(kf, qf[c], s, 0, 0, 0);
        }
        __builtin_amdgcn_s_setprio(0);

        // ---- P = exp2(S*SC) in-register; pack bf16 pairs; half-swap into A-frags
        unsigned int w[8];
#pragma unroll
        for (int i = 0; i < 8; ++i) {
            float pa = exp2f(s[2 * i]     * SC);
            float pb = exp2f(s[2 * i + 1] * SC);
            lpA += pa; lpB += pb;
            w[i] = cvtpk(pa, pb);
        }
        unsigned int t0 = __shfl_xor(h ? w[0] : w[2], 32);
        unsigned int t1 = __shfl_xor(h ? w[1] : w[3], 32);
        unsigned int t2 = __shfl_xor(h ? w[4] : w[6], 32);
        unsigned int t3 = __shfl_xor(h ? w[5] : w[7], 32);
        bf16x8 pf0 = frag4(h ? t0 : w[0], h ? t1 : w[1], h ? w[2] : t0, h ? w[3] : t1);
        bf16x8 pf1 = frag4(h ? t2 : w[4], h ? t3 : w[5], h ? w[6] : t2, h ? w[7] : t3);

        // ---- O += P*V
        __builtin_amdgcn_s_setprio(1);
#pragma unroll
        for (int dt = 0; dt < 4; ++dt) {
            const int d  = dt * 32 + l32;
            const int sw = (d >> 1) & 3;
            bf16x8 v0 = ldb(Vt + d * 32 + ((h    ) ^ sw) * 8);
            bf16x8 v1 = ldb(Vt + d * 32 + ((2 + h) ^ sw) * 8);
            oacc[dt] = __builtin_amdgcn_mfma_f32_32x32x16_bf16(pf0, v0, oacc[dt], 0, 0, 0);
            oacc[dt] = __builtin_amdgcn_mfma_f32_32x32x16_bf16(pf1, v1, oacc[dt], 0, 0, 0);
        }
        __builtin_amdgcn_s_setprio(0);

        asm volatile("s_waitcnt vmcnt(0)" ::: "memory");   // own stage loads landed
        __builtin_amdgcn_s_barrier();                      // tile t+1 visible / t fully read
        asm volatile("" ::: "memory");
    }
#undef STAGE

    // ---- write partials: numerator (f32) + denominator per q-row
    float lp2 = lpA + lpB;
    lp2 += __shfl_xor(lp2, 32);
    if (h == 0)
        Lpart[(size_t)ks * (BATCH * SEQ) + (size_t)b * SEQ + q0 + l32] = lp2;
    float* Op = Opart + (size_t)ks * NELEM;
#pragma unroll
    for (int dt = 0; dt < 4; ++dt)
#pragma unroll
        for (int r = 0; r < 16; ++r) {
            const int qr = (r & 3) + 8 * (r >> 2) + 4 * h;
            Op[(qbase + qr) * DH + dt * 32 + l32] = oacc[dt][r];
        }
}

// merge the 4 ks-planes: O = (sum Op) / (sum L)
__global__ __launch_bounds__(256)
void merge_split(const float* __restrict__ Opart, const float* __restrict__ Lpart,
                 float* __restrict__ O)
{
    const size_t g  = (size_t)blockIdx.x * 256 + threadIdx.x;   // 1,048,576 threads
    const size_t i4 = g * 4;
    const size_t bq = i4 >> 7;                                  // b*SEQ + q
    float L = Lpart[bq] + Lpart[BATCH * SEQ + bq] +
              Lpart[2 * BATCH * SEQ + bq] + Lpart[3 * BATCH * SEQ + bq];
    const float inv = 1.0f / L;
    f32x4 a = *(const f32x4*)&Opart[i4];
    f32x4 b1 = *(const f32x4*)&Opart[NELEM + i4];
    f32x4 c = *(const f32x4*)&Opart[2 * NELEM + i4];
    f32x4 d = *(const f32x4*)&Opart[3 * NELEM + i4];
#pragma unroll
    for (int j = 0; j < 4; ++j) a[j] = (a[j] + b1[j] + c[j] + d[j]) * inv;
    *(f32x4*)&O[i4] = a;
}

// ==================================================================================
// LEGACY PATH (proven R3, 124us): 512 blocks, 2 kh-streams in-block, LDS merge.
// Used when ws is too small for split-K partials.
// ==================================================================================
__device__ __forceinline__ void issue_stage(const unsigned short* __restrict__ Kbf,
                                            const unsigned short* __restrict__ Vtg,
                                            unsigned short* sm16, int b, int kh, int qh,
                                            int lane, int t)
{
    const int buf = t & 1;
    const int kb  = kh * 2048 + t * 32;
    const int rin = lane >> 4;
    const int sb  = (lane & 15) << 4;
    const unsigned short* Kb = Kbf + (size_t)b * SEQ * DH;
#pragma unroll
    for (int ch = 0; ch < 4; ++ch) {
        const int row = qh * 16 + ch * 4 + rin;
        const unsigned char* src =
            (const unsigned char*)(Kb + (size_t)(kb + row) * DH) + (sb ^ ((row & 7) << 4));
        unsigned short* dst = sm16 + (kh * 2 + buf) * 4096 + (qh * 16 + ch * 4) * 128;
        gll16(src, dst);
    }
    const unsigned short* Vb = Vtg + (size_t)b * DH * SEQ;
    const int vr = lane >> 2, vs = lane & 3;
#pragma unroll
    for (int ch = 0; ch < 4; ++ch) {
        const int row = qh * 64 + ch * 16 + vr;
        const int slot = vs ^ ((row >> 1) & 3);
        const unsigned short* src = Vb + (size_t)row * SEQ + kb + slot * 8;
        unsigned short* dst = sm16 + OFF_V + (kh * 2 + buf) * 4096 + (qh * 64 + ch * 16) * 32;
        gll16(src, dst);
    }
}

__device__ __forceinline__ void stage_fallback(const float* __restrict__ Kg,
                                               const float* __restrict__ Vg,
                                               unsigned short* sm16, int b, int tid, int t)
{
    const int buf = t & 1;
#pragma unroll
    for (int s = 0; s < 2; ++s) {
        const int kb = s * 2048 + t * 32;
        {
            int r = tid >> 3, cg = tid & 7;
            const float* sp = Kg + ((size_t)b * SEQ + kb + r) * DH + cg * 16;
            ushort8 lo = cvt8(sp), hi = cvt8(sp + 8);
            unsigned char* kd = (unsigned char*)(sm16 + (s * 2 + buf) * 4096) + r * 256;
            int sbb = cg * 32, m = (r & 7) << 4;
            *(ushort8*)(kd + (sbb ^ m))        = lo;
            *(ushort8*)(kd + ((sbb + 16) ^ m)) = hi;
        }
        {
            int d = tid >> 1, half = tid & 1, sw = (d >> 1) & 3;
            ushort8 a, c;
#pragma unroll
            for (int j = 0; j < 8; ++j) {
                a[j] = f2bf(Vg[((size_t)b * SEQ + kb + half * 16 + j) * DH + d]);
                c[j] = f2bf(Vg[((size_t)b * SEQ + kb + half * 16 + 8 + j) * DH + d]);
            }
            unsigned short* vd = sm16 + OFF_V + (s * 2 + buf) * 4096 + d * 32;
            *(ushort8*)(vd + ((half * 2    ) ^ sw) * 8) = a;
            *(ushort8*)(vd + ((half * 2 + 1) ^ sw) * 8) = c;
        }
    }
}

template<int PREP>
__device__ __forceinline__ void attn_body32(
    const float* __restrict__ Qg, const float* __restrict__ Kg,
    const float* __restrict__ Vg,
    const unsigned short* __restrict__ Kbf, const unsigned short* __restrict__ Vtg,
    float* __restrict__ Og, unsigned short* sm16, int b, int qt5)
{
    const int tid  = threadIdx.x;
    const int wv   = tid >> 6;
    const int lane = tid & 63;
    const int l32  = lane & 31;
    const int h    = lane >> 5;
    const int qh = wv & 1;
    const int kh = wv >> 1;

    const size_t qbase = (size_t)b * SEQ + (size_t)qt5 * 64 + qh * 32;

    bf16x8 qf[8];
#pragma unroll
    for (int c = 0; c < 8; ++c)
        qf[c] = __builtin_bit_cast(bf16x8, cvt8(Qg + (qbase + l32) * DH + c * 16 + h * 8));

    f32x16 oacc[4];
#pragma unroll
    for (int dt = 0; dt < 4; ++dt)
#pragma unroll
        for (int r = 0; r < 16; ++r) oacc[dt][r] = 0.f;
    float lpA = 0.f, lpB = 0.f;
    const int swzK = (l32 & 7) << 4;

    asm volatile("s_waitcnt vmcnt(0)" ::: "memory");
    if (PREP) issue_stage(Kbf, Vtg, sm16, b, kh, qh, lane, 0);
    else      stage_fallback(Kg, Vg, sm16, b, tid, 0);

    for (int t = 0; t < 64; ++t) {
        __builtin_amdgcn_s_barrier();
        asm volatile("" ::: "memory");
        if (PREP) {
            if (t < 63) {
                issue_stage(Kbf, Vtg, sm16, b, kh, qh, lane, t + 1);
                asm volatile("s_waitcnt vmcnt(8)" ::: "memory");
            } else {
                asm volatile("s_waitcnt vmcnt(0)" ::: "memory");
            }
        } else {
            if (t < 63) stage_fallback(Kg, Vg, sm16, b, tid, t + 1);
            asm volatile("s_waitcnt vmcnt(0) lgkmcnt(0)" ::: "memory");
        }
        __builtin_amdgcn_s_barrier();
        asm volatile("" ::: "memory");

        const unsigned char*  Kbb = (const unsigned char*)(sm16 + (kh * 2 + (t & 1)) * 4096);
        const unsigned short* Vt  = sm16 + OFF_V + (kh * 2 + (t & 1)) * 4096;

        __builtin_amdgcn_s_setprio(1);
        f32x16 s;
#pragma unroll
        for (int r = 0; r < 16; ++r) s[r] = 0.f;
#pragma unroll
        for (int c = 0; c < 8; ++c) {
            bf16x8 kf = ldb((const unsigned short*)(Kbb + l32 * 256 + ((c * 32 + h * 16) ^ swzK)));
            s = __builtin_amdgcn_mfma_f32_32x32x16_bf16(kf, qf[c], s, 0, 0, 0);
        }
        __builtin_amdgcn_s_setprio(0);

        unsigned int w[8];
#pragma unroll
        for (int i = 0; i < 8; ++i) {
            float pa = exp2f(s[2 * i]     * SC);
            float pb = exp2f(s[2 * i + 1] * SC);
            lpA += pa; lpB += pb;
            w[i] = cvtpk(pa, pb);
        }
        unsigned int t0 = __shfl_xor(h ? w[0] : w[2], 32);
        unsigned int t1 = __shfl_xor(h ? w[1] : w[3], 32);
        unsigned int t2 = __shfl_xor(h ? w[4] : w[6], 32);
        unsigned int t3 = __shfl_xor(h ? w[5] : w[7], 32);
        bf16x8 pf0 = frag4(h ? t0 : w[0], h ? t1 : w[1], h ? w[2] : t0, h ? w[3] : t1);
        bf16x8 pf1 = frag4(h ? t2 : w[4], h ? t3 : w[5], h ? w[6] : t2, h ? w[7] : t3);

        __builtin_amdgcn_s_setprio(1);
#pragma unroll
        for (int dt = 0; dt < 4; ++dt) {
            const int d  = dt * 32 + l32;
            const int sw = (d >> 1) & 3;
            bf16x8 v0 = ldb(Vt + d * 32 + ((h    ) ^ sw) * 8);
            bf16x8 v1 = ldb(Vt + d * 32 + ((2 + h) ^ sw) * 8);
            oacc[dt] = __builtin_amdgcn_mfma_f32_32x32x16_bf16(pf0, v0, oacc[dt], 0, 0, 0);
            oacc[dt] = __builtin_amdgcn_mfma_f32_32x32x16_bf16(pf1, v1, oacc[dt], 0, 0, 0);
        }
        __builtin_amdgcn_s_setprio(0);
    }

    float lp2 = lpA + lpB;
    lp2 += __shfl_xor(lp2, 32);
    float* Om = (float*)sm16;
    float* lb = (float*)((char*)sm16 + 65536);
    __syncthreads();
    if (h == 0) lb[kh * 64 + qh * 32 + l32] = lp2;
    if (kh == 1) {
#pragma unroll
        for (int dt = 0; dt < 4; ++dt)
#pragma unroll
            for (int r = 0; r < 16; ++r) {
                const int qr = (r & 3) + 8 * (r >> 2) + 4 * h;
                Om[(qh * 32 + qr) * 128 + dt * 32 + l32] = oacc[dt][r];
            }
    }
    __syncthreads();
    if (kh == 0) {
        float invr[16];
#pragma unroll
        for (int r = 0; r < 16; ++r) {
            const int qr = (r & 3) + 8 * (r >> 2) + 4 * h;
            invr[r] = 1.0f / (lb[qh * 32 + qr] + lb[64 + qh * 32 + qr]);
        }
#pragma unroll
        for (int dt = 0; dt < 4; ++dt)
#pragma unroll
            for (int r = 0; r < 16; ++r) {
                const int qr = (r & 3) + 8 * (r >> 2) + 4 * h;
                Og[(qbase + qr) * DH + dt * 32 + l32] =
                    (oacc[dt][r] + Om[(qh * 32 + qr) * 128 + dt * 32 + l32]) * invr[r];
            }
    }
}

__global__ __launch_bounds__(256, 2)
void attn_fwd(const float* __restrict__ Qg, const float* __restrict__ Kg,
              const float* __restrict__ Vg,
              const unsigned short* __restrict__ Kbf,
              const unsigned short* __restrict__ Vtg,
              float* __restrict__ Og, int prep)
{
    extern __shared__ __align__(16) unsigned char smem[];
    unsigned short* sm16 = (unsigned short*)smem;

    const int b   = blockIdx.x & 7;
    const int qt5 = blockIdx.x >> 3;

    if (prep) attn_body32<1>(Qg, Kg, Vg, Kbf, Vtg, Og, sm16, b, qt5);
    else      attn_body32<0>(Qg, Kg, Vg, Kbf, Vtg, Og, sm16, b, qt5);
}

extern "C" void kernel_launch(void* const* d_in, const int* in_sizes, int n_in,
                              void* d_out, int out_size, void* d_ws, size_t ws_size,
                              hipStream_t stream) {
    const float* Q = (const float*)d_in[0];
    const float* K = (const float*)d_in[1];
    const float* V = (const float*)d_in[2];
    float* O = (float*)d_out;

    const size_t prep_bytes  = NELEM * 2 * 2;                          // 16,777,216
    const size_t split_bytes = prep_bytes + KSPLIT * NELEM * 4         // partials
                             + (size_t)KSPLIT * BATCH * SEQ * 4;       // L
    const bool prep  = (ws_size >= prep_bytes);
    const bool split = (ws_size >= split_bytes);

    unsigned short* Kbf = (unsigned short*)d_ws;
    unsigned short* Vtg = Kbf + NELEM;
    float* Opart = (float*)(Kbf + 2 * NELEM);
    float* Lpart = Opart + KSPLIT * NELEM;

    static int smem_cfged = 0;
    if (!smem_cfged) {
        (void)hipFuncSetAttribute((const void*)attn_fwd,
                                  hipFuncAttributeMaxDynamicSharedMemorySize, SMEM_BYTES);
        smem_cfged = 1;
    }

    if (prep)
        prep_all<<<dim3(2048 + BATCH * 128 * 4), 256, 0, stream>>>(K, V, Kbf, Vtg);

    if (split) {
        attn_split<<<dim3(BATCH * 32 * KSPLIT), 256, 0, stream>>>(Q, Kbf, Vtg, Opart, Lpart);
        merge_split<<<dim3(NELEM / (256 * 4)), 256, 0, stream>>>(Opart, Lpart, O);
    } else {
        attn_fwd<<<dim3(BATCH * (SEQ / 64)), 256, SMEM_BYTES, stream>>>(Q, K, V, Kbf, Vtg, O, prep ? 1 : 0);
    }
}

// Round 7
// 187.225 us; speedup vs baseline: 1.5910x; 1.0202x over previous
//
#include <hip/hip_runtime.h>

typedef __bf16 bf16x8 __attribute__((ext_vector_type(8)));
typedef float f32x4 __attribute__((ext_vector_type(4)));
typedef float f32x16 __attribute__((ext_vector_type(16)));
typedef unsigned short ushort8 __attribute__((ext_vector_type(8)));
typedef unsigned int uint4v __attribute__((ext_vector_type(4)));

#define BATCH 8
#define SEQ 4096
#define DH 128
#define NELEM 4194304ull     // BATCH*SEQ*DH
#define KSPLIT 3             // uneven: 43/43/42 chunks of 32 keys
#define SC (0.08838834764831845f * 1.4426950408889634f)

// ---- legacy dynamic-LDS map (u16 units), proven R3 path ----
#define OFF_V 16384
#define SMEM_BYTES 75776

__device__ __forceinline__ unsigned short f2bf(float x) {
    unsigned int u = __builtin_bit_cast(unsigned int, x);
    u = (u + 0x7FFFu + ((u >> 16) & 1u)) >> 16;
    return (unsigned short)u;
}
__device__ __forceinline__ ushort8 cvt8(const float* __restrict__ p) {
    f32x4 a = *(const f32x4*)p;
    f32x4 b = *(const f32x4*)(p + 4);
    ushort8 r;
    r[0] = f2bf(a[0]); r[1] = f2bf(a[1]); r[2] = f2bf(a[2]); r[3] = f2bf(a[3]);
    r[4] = f2bf(b[0]); r[5] = f2bf(b[1]); r[6] = f2bf(b[2]); r[7] = f2bf(b[3]);
    return r;
}
__device__ __forceinline__ bf16x8 ldb(const unsigned short* p) {
    return __builtin_bit_cast(bf16x8, *(const ushort8*)p);
}
__device__ __forceinline__ void gll16(const void* src, void* dst) {
    __builtin_amdgcn_global_load_lds((const __attribute__((address_space(1))) unsigned int*)src,
                                     (__attribute__((address_space(3))) unsigned int*)dst, 16, 0, 0);
}
__device__ __forceinline__ unsigned int cvtpk(float lo, float hi) {
    unsigned int r;
    asm("v_cvt_pk_bf16_f32 %0, %1, %2" : "=v"(r) : "v"(lo), "v"(hi));
    return r;
}
__device__ __forceinline__ bf16x8 frag4(unsigned int a, unsigned int b,
                                        unsigned int c, unsigned int d) {
    uint4v u; u[0] = a; u[1] = b; u[2] = c; u[3] = d;
    return __builtin_bit_cast(bf16x8, u);
}

// ---------------- merged prep kernel: K->bf16, V->bf16 transposed ----------------
__global__ __launch_bounds__(256) void prep_all(const float* __restrict__ Kg,
                                                const float* __restrict__ Vg,
                                                unsigned short* __restrict__ Kbf,
                                                unsigned short* __restrict__ Vtg) {
    __shared__ float T[32 * 36];
    if (blockIdx.x < 2048) {
        size_t i = ((size_t)blockIdx.x * 256 + threadIdx.x) * 8;
        *(ushort8*)(Kbf + i) = cvt8(Kg + i);
        return;
    }
    const int bid = blockIdx.x - 2048;
    const int b  = bid >> 9;
    const int kt = (bid >> 2) & 127;
    const int dt = bid & 3;
    const int tid = threadIdx.x;
    {
        int r = tid >> 3, c4 = (tid & 7) * 4;
        f32x4 v = *(const f32x4*)(Vg + ((size_t)b * SEQ + kt * 32 + r) * DH + dt * 32 + c4);
        *(f32x4*)(&T[r * 36 + c4]) = v;
    }
    __syncthreads();
    {
        int rd = tid >> 3, kc4 = (tid & 7) * 4;
        unsigned long long w = 0;
#pragma unroll
        for (int j = 0; j < 4; ++j)
            w |= (unsigned long long)f2bf(T[(kc4 + j) * 36 + rd]) << (16 * j);
        *(unsigned long long*)(Vtg + ((size_t)b * DH + dt * 32 + rd) * SEQ + kt * 32 + kc4) = w;
    }
}

// ==================================================================================
// SPLIT-K PATH, residency-even: 768 blocks (8b x 32qt x 3ks) = exactly 3 blocks/CU
// at ~164 total regs (launch_bounds(256,3), cap 170). Uneven key chunks 43/43/42 x32.
// 3-buffer LDS (48 KB), 2-deep prefetch, ONE barrier + counted vmcnt(4) per step.
// LDS map (u16): K[buf] at buf*4096 (3 bufs, 32 key-rows x 256B, src-swz byte^=(row&7)<<4)
//                V[buf] at 12288+buf*4096 (128 d-rows x 64B, slot^=(row>>1)&3)
// ==================================================================================
__global__ __launch_bounds__(256, 3)
void attn_split(const float* __restrict__ Qg,
                const unsigned short* __restrict__ Kbf,
                const unsigned short* __restrict__ Vtg,
                float* __restrict__ Opart, float* __restrict__ Lpart)
{
    __shared__ __align__(16) unsigned short sm16[24576];   // 48 KB

    const int tid  = threadIdx.x;
    const int wv   = tid >> 6;
    const int lane = tid & 63;
    const int l32  = lane & 31;
    const int h    = lane >> 5;

    const int b  = blockIdx.x & 7;          // batch -> XCD slot (K/V L2 locality)
    const int rr = blockIdx.x >> 3;         // 0..95
    const int ks = rr & 3;                  // 0..2 (rr = qt*3+ks arrangement below)
    // rr in [0,96): ks = rr - (rr/3)*3 ; qt = rr/3  (avoid %: 96 = 32*3)
    const int qt  = rr / 3;
    const int ks3 = rr - qt * 3;
    const int NT  = (ks3 < 2) ? 43 : 42;    // key chunks this block
    const int kb0 = ks3 * 43 * 32;          // start key

    const int q0 = qt * 128 + wv * 32;
    const size_t qbase = (size_t)b * SEQ + q0;

    // Q as B-operand: B[k][n=q], n = l32 -> row qbase+l32 ; k = h*8+j per d-chunk c
    bf16x8 qf[8];
#pragma unroll
    for (int c = 0; c < 8; ++c)
        qf[c] = __builtin_bit_cast(bf16x8, cvt8(Qg + (qbase + l32) * DH + c * 16 + h * 8));

    f32x16 oacc[4];
#pragma unroll
    for (int dt = 0; dt < 4; ++dt)
#pragma unroll
        for (int r = 0; r < 16; ++r) oacc[dt][r] = 0.f;
    float lpA = 0.f, lpB = 0.f;
    const int swzK = (l32 & 7) << 4;

    // persistent staging source pointers (role by wave: wv<2 -> K halves, else V halves)
    const unsigned char* srcp[4];
    long sstr;
    if (wv < 2) {
        const unsigned short* Kb = Kbf + (size_t)b * SEQ * DH;
#pragma unroll
        for (int ch = 0; ch < 4; ++ch) {
            const int row  = wv * 16 + ch * 4 + (lane >> 4);
            const int colb = ((lane & 15) << 4) ^ ((row & 7) << 4);
            srcp[ch] = (const unsigned char*)(Kb + (size_t)(kb0 + row) * DH) + colb;
        }
        sstr = 32 * DH * 2;        // 8192 B per step
    } else {
        const unsigned short* Vb = Vtg + (size_t)b * DH * SEQ;
#pragma unroll
        for (int ch = 0; ch < 4; ++ch) {
            const int row  = (wv - 2) * 64 + ch * 16 + (lane >> 2);
            const int slot = (lane & 3) ^ ((row >> 1) & 3);
            srcp[ch] = (const unsigned char*)(Vb + (size_t)row * SEQ + kb0 + slot * 8);
        }
        sstr = 64;                 // 32 keys * 2 B per step
    }

    // stage one tile quarter (4 x gll, 1KB each) into 3-buffer ring; advance sources
#define STAGE(bufv)                                                                 \
    {                                                                               \
        unsigned short* bse = (wv < 2)                                              \
            ? sm16 + (bufv) * 4096 + wv * 2048                                      \
            : sm16 + 12288 + (bufv) * 4096 + (wv - 2) * 2048;                       \
        _Pragma("unroll")                                                           \
        for (int ch = 0; ch < 4; ++ch) {                                            \
            gll16(srcp[ch], bse + ch * 512);                                        \
            srcp[ch] += sstr;                                                       \
        }                                                                           \
    }

    asm volatile("s_waitcnt vmcnt(0)" ::: "memory");   // Q loads drained
    STAGE(0);
    STAGE(1);

    int buf = 0, stg = 2;
    for (int t = 0; t < NT; ++t) {
        // tile t landed when only tile t+1's 4 loads remain outstanding
        if (t + 1 < NT) { asm volatile("s_waitcnt vmcnt(4)" ::: "memory"); }
        else            { asm volatile("s_waitcnt vmcnt(0)" ::: "memory"); }
        __builtin_amdgcn_s_barrier();       // all waves' tile-t loads landed; compute(t-1) done
        asm volatile("" ::: "memory");

        const unsigned char*  Kbb = (const unsigned char*)(sm16 + buf * 4096);
        const unsigned short* Vt  = sm16 + 12288 + buf * 4096;

        // ---- S^T = K * Q^T : 32key x 32q, lane-local q-row (swapped operands)
        __builtin_amdgcn_s_setprio(1);
        f32x16 s;
#pragma unroll
        for (int r = 0; r < 16; ++r) s[r] = 0.f;
#pragma unroll
        for (int c = 0; c < 8; ++c) {
            bf16x8 kf = ldb((const unsigned short*)(Kbb + l32 * 256 + ((c * 32 + h * 16) ^ swzK)));
            s = __builtin_amdgcn_mfma_f32_32x32x16_bf16(kf, qf[c], s, 0, 0, 0);
        }
        __builtin_amdgcn_s_setprio(0);

        // ---- P = exp2(S*SC) in-register; pack bf16 pairs; half-swap into A-frags
        unsigned int w[8];
#pragma unroll
        for (int i = 0; i < 8; ++i) {
            float pa = exp2f(s[2 * i]     * SC);
            float pb = exp2f(s[2 * i + 1] * SC);
            lpA += pa; lpB += pb;
            w[i] = cvtpk(pa, pb);
        }
        unsigned int t0 = __shfl_xor(h ? w[0] : w[2], 32);
        unsigned int t1 = __shfl_xor(h ? w[1] : w[3], 32);
        unsigned int t2 = __shfl_xor(h ? w[4] : w[6], 32);
        unsigned int t3 = __shfl_xor(h ? w[5] : w[7], 32);
        bf16x8 pf0 = frag4(h ? t0 : w[0], h ? t1 : w[1], h ? w[2] : t0, h ? w[3] : t1);
        bf16x8 pf1 = frag4(h ? t2 : w[4], h ? t3 : w[5], h ? w[6] : t2, h ? w[7] : t3);

        // ---- O += P*V
        __builtin_amdgcn_s_setprio(1);
#pragma unroll
        for (int dt = 0; dt < 4; ++dt) {
            const int d  = dt * 32 + l32;
            const int sw = (d >> 1) & 3;
            bf16x8 v0 = ldb(Vt + d * 32 + ((h    ) ^ sw) * 8);
            bf16x8 v1 = ldb(Vt + d * 32 + ((2 + h) ^ sw) * 8);
            oacc[dt] = __builtin_amdgcn_mfma_f32_32x32x16_bf16(pf0, v0, oacc[dt], 0, 0, 0);
            oacc[dt] = __builtin_amdgcn_mfma_f32_32x32x16_bf16(pf1, v1, oacc[dt], 0, 0, 0);
        }
        __builtin_amdgcn_s_setprio(0);

        // issue tile t+2 into the buffer compute(t-1) finished with (entry barrier ordered it)
        if (t + 2 < NT) { STAGE(stg); }
        buf = (buf == 2) ? 0 : buf + 1;
        stg = (stg == 2) ? 0 : stg + 1;
    }
#undef STAGE

    // ---- write partials: numerator (f32) + denominator per q-row
    float lp2 = lpA + lpB;
    lp2 += __shfl_xor(lp2, 32);
    if (h == 0)
        Lpart[(size_t)ks3 * (BATCH * SEQ) + (size_t)b * SEQ + q0 + l32] = lp2;
    float* Op = Opart + (size_t)ks3 * NELEM;
#pragma unroll
    for (int dt = 0; dt < 4; ++dt)
#pragma unroll
        for (int r = 0; r < 16; ++r) {
            const int qr = (r & 3) + 8 * (r >> 2) + 4 * h;
            Op[(qbase + qr) * DH + dt * 32 + l32] = oacc[dt][r];
        }
    (void)ks;
}

// merge the 3 ks-planes: O = (sum Op) / (sum L)
__global__ __launch_bounds__(256)
void merge_split(const float* __restrict__ Opart, const float* __restrict__ Lpart,
                 float* __restrict__ O)
{
    const size_t g  = (size_t)blockIdx.x * 256 + threadIdx.x;   // 1,048,576 threads
    const size_t i4 = g * 4;
    const size_t bq = i4 >> 7;                                  // b*SEQ + q
    float L = Lpart[bq] + Lpart[BATCH * SEQ + bq] + Lpart[2 * BATCH * SEQ + bq];
    const float inv = 1.0f / L;
    f32x4 a  = *(const f32x4*)&Opart[i4];
    f32x4 b1 = *(const f32x4*)&Opart[NELEM + i4];
    f32x4 c  = *(const f32x4*)&Opart[2 * NELEM + i4];
#pragma unroll
    for (int j = 0; j < 4; ++j) a[j] = (a[j] + b1[j] + c[j]) * inv;
    *(f32x4*)&O[i4] = a;
}

// ==================================================================================
// LEGACY PATH (proven R3, 124us): 512 blocks, 2 kh-streams in-block, LDS merge.
// Used when ws is too small for split-K partials.
// ==================================================================================
__device__ __forceinline__ void issue_stage(const unsigned short* __restrict__ Kbf,
                                            const unsigned short* __restrict__ Vtg,
                                            unsigned short* sm16, int b, int kh, int qh,
                                            int lane, int t)
{
    const int buf = t & 1;
    const int kb  = kh * 2048 + t * 32;
    const int rin = lane >> 4;
    const int sb  = (lane & 15) << 4;
    const unsigned short* Kb = Kbf + (size_t)b * SEQ * DH;
#pragma unroll
    for (int ch = 0; ch < 4; ++ch) {
        const int row = qh * 16 + ch * 4 + rin;
        const unsigned char* src =
            (const unsigned char*)(Kb + (size_t)(kb + row) * DH) + (sb ^ ((row & 7) << 4));
        unsigned short* dst = sm16 + (kh * 2 + buf) * 4096 + (qh * 16 + ch * 4) * 128;
        gll16(src, dst);
    }
    const unsigned short* Vb = Vtg + (size_t)b * DH * SEQ;
    const int vr = lane >> 2, vs = lane & 3;
#pragma unroll
    for (int ch = 0; ch < 4; ++ch) {
        const int row = qh * 64 + ch * 16 + vr;
        const int slot = vs ^ ((row >> 1) & 3);
        const unsigned short* src = Vb + (size_t)row * SEQ + kb + slot * 8;
        unsigned short* dst = sm16 + OFF_V + (kh * 2 + buf) * 4096 + (qh * 64 + ch * 16) * 32;
        gll16(src, dst);
    }
}

__device__ __forceinline__ void stage_fallback(const float* __restrict__ Kg,
                                               const float* __restrict__ Vg,
                                               unsigned short* sm16, int b, int tid, int t)
{
    const int buf = t & 1;
#pragma unroll
    for (int s = 0; s < 2; ++s) {
        const int kb = s * 2048 + t * 32;
        {
            int r = tid >> 3, cg = tid & 7;
            const float* sp = Kg + ((size_t)b * SEQ + kb + r) * DH + cg * 16;
            ushort8 lo = cvt8(sp), hi = cvt8(sp + 8);
            unsigned char* kd = (unsigned char*)(sm16 + (s * 2 + buf) * 4096) + r * 256;
            int sbb = cg * 32, m = (r & 7) << 4;
            *(ushort8*)(kd + (sbb ^ m))        = lo;
            *(ushort8*)(kd + ((sbb + 16) ^ m)) = hi;
        }
        {
            int d = tid >> 1, half = tid & 1, sw = (d >> 1) & 3;
            ushort8 a, c;
#pragma unroll
            for (int j = 0; j < 8; ++j) {
                a[j] = f2bf(Vg[((size_t)b * SEQ + kb + half * 16 + j) * DH + d]);
                c[j] = f2bf(Vg[((size_t)b * SEQ + kb + half * 16 + 8 + j) * DH + d]);
            }
            unsigned short* vd = sm16 + OFF_V + (s * 2 + buf) * 4096 + d * 32;
            *(ushort8*)(vd + ((half * 2    ) ^ sw) * 8) = a;
            *(ushort8*)(vd + ((half * 2 + 1) ^ sw) * 8) = c;
        }
    }
}

template<int PREP>
__device__ __forceinline__ void attn_body32(
    const float* __restrict__ Qg, const float* __restrict__ Kg,
    const float* __restrict__ Vg,
    const unsigned short* __restrict__ Kbf, const unsigned short* __restrict__ Vtg,
    float* __restrict__ Og, unsigned short* sm16, int b, int qt5)
{
    const int tid  = threadIdx.x;
    const int wv   = tid >> 6;
    const int lane = tid & 63;
    const int l32  = lane & 31;
    const int h    = lane >> 5;
    const int qh = wv & 1;
    const int kh = wv >> 1;

    const size_t qbase = (size_t)b * SEQ + (size_t)qt5 * 64 + qh * 32;

    bf16x8 qf[8];
#pragma unroll
    for (int c = 0; c < 8; ++c)
        qf[c] = __builtin_bit_cast(bf16x8, cvt8(Qg + (qbase + l32) * DH + c * 16 + h * 8));

    f32x16 oacc[4];
#pragma unroll
    for (int dt = 0; dt < 4; ++dt)
#pragma unroll
        for (int r = 0; r < 16; ++r) oacc[dt][r] = 0.f;
    float lpA = 0.f, lpB = 0.f;
    const int swzK = (l32 & 7) << 4;

    asm volatile("s_waitcnt vmcnt(0)" ::: "memory");
    if (PREP) issue_stage(Kbf, Vtg, sm16, b, kh, qh, lane, 0);
    else      stage_fallback(Kg, Vg, sm16, b, tid, 0);

    for (int t = 0; t < 64; ++t) {
        __builtin_amdgcn_s_barrier();
        asm volatile("" ::: "memory");
        if (PREP) {
            if (t < 63) {
                issue_stage(Kbf, Vtg, sm16, b, kh, qh, lane, t + 1);
                asm volatile("s_waitcnt vmcnt(8)" ::: "memory");
            } else {
                asm volatile("s_waitcnt vmcnt(0)" ::: "memory");
            }
        } else {
            if (t < 63) stage_fallback(Kg, Vg, sm16, b, tid, t + 1);
            asm volatile("s_waitcnt vmcnt(0) lgkmcnt(0)" ::: "memory");
        }
        __builtin_amdgcn_s_barrier();
        asm volatile("" ::: "memory");

        const unsigned char*  Kbb = (const unsigned char*)(sm16 + (kh * 2 + (t & 1)) * 4096);
        const unsigned short* Vt  = sm16 + OFF_V + (kh * 2 + (t & 1)) * 4096;

        __builtin_amdgcn_s_setprio(1);
        f32x16 s;
#pragma unroll
        for (int r = 0; r < 16; ++r) s[r] = 0.f;
#pragma unroll
        for (int c = 0; c < 8; ++c) {
            bf16x8 kf = ldb((const unsigned short*)(Kbb + l32 * 256 + ((c * 32 + h * 16) ^ swzK)));
            s = __builtin_amdgcn_mfma_f32_32x32x16_bf16(kf, qf[c], s, 0, 0, 0);
        }
        __builtin_amdgcn_s_setprio(0);

        unsigned int w[8];
#pragma unroll
        for (int i = 0; i < 8; ++i) {
            float pa = exp2f(s[2 * i]     * SC);
            float pb = exp2f(s[2 * i + 1] * SC);
            lpA += pa; lpB += pb;
            w[i] = cvtpk(pa, pb);
        }
        unsigned int t0 = __shfl_xor(h ? w[0] : w[2], 32);
        unsigned int t1 = __shfl_xor(h ? w[1] : w[3], 32);
        unsigned int t2 = __shfl_xor(h ? w[4] : w[6], 32);
        unsigned int t3 = __shfl_xor(h ? w[5] : w[7], 32);
        bf16x8 pf0 = frag4(h ? t0 : w[0], h ? t1 : w[1], h ? w[2] : t0, h ? w[3] : t1);
        bf16x8 pf1 = frag4(h ? t2 : w[4], h ? t3 : w[5], h ? w[6] : t2, h ? w[7] : t3);

        __builtin_amdgcn_s_setprio(1);
#pragma unroll
        for (int dt = 0; dt < 4; ++dt) {
            const int d  = dt * 32 + l32;
            const int sw = (d >> 1) & 3;
            bf16x8 v0 = ldb(Vt + d * 32 + ((h    ) ^ sw) * 8);
            bf16x8 v1 = ldb(Vt + d * 32 + ((2 + h) ^ sw) * 8);
            oacc[dt] = __builtin_amdgcn_mfma_f32_32x32x16_bf16(pf0, v0, oacc[dt], 0, 0, 0);
            oacc[dt] = __builtin_amdgcn_mfma_f32_32x32x16_bf16(pf1, v1, oacc[dt], 0, 0, 0);
        }
        __builtin_amdgcn_s_setprio(0);
    }

    float lp2 = lpA + lpB;
    lp2 += __shfl_xor(lp2, 32);
    float* Om = (float*)sm16;
    float* lb = (float*)((char*)sm16 + 65536);
    __syncthreads();
    if (h == 0) lb[kh * 64 + qh * 32 + l32] = lp2;
    if (kh == 1) {
#pragma unroll
        for (int dt = 0; dt < 4; ++dt)
#pragma unroll
            for (int r = 0; r < 16; ++r) {
                const int qr = (r & 3) + 8 * (r >> 2) + 4 * h;
                Om[(qh * 32 + qr) * 128 + dt * 32 + l32] = oacc[dt][r];
            }
    }
    __syncthreads();
    if (kh == 0) {
        float invr[16];
#pragma unroll
        for (int r = 0; r < 16; ++r) {
            const int qr = (r & 3) + 8 * (r >> 2) + 4 * h;
            invr[r] = 1.0f / (lb[qh * 32 + qr] + lb[64 + qh * 32 + qr]);
        }
#pragma unroll
        for (int dt = 0; dt < 4; ++dt)
#pragma unroll
            for (int r = 0; r < 16; ++r) {
                const int qr = (r & 3) + 8 * (r >> 2) + 4 * h;
                Og[(qbase + qr) * DH + dt * 32 + l32] =
                    (oacc[dt][r] + Om[(qh * 32 + qr) * 128 + dt * 32 + l32]) * invr[r];
            }
    }
}

__global__ __launch_bounds__(256, 2)
void attn_fwd(const float* __restrict__ Qg, const float* __restrict__ Kg,
              const float* __restrict__ Vg,
              const unsigned short* __restrict__ Kbf,
              const unsigned short* __restrict__ Vtg,
              float* __restrict__ Og, int prep)
{
    extern __shared__ __align__(16) unsigned char smem[];
    unsigned short* sm16 = (unsigned short*)smem;

    const int b   = blockIdx.x & 7;
    const int qt5 = blockIdx.x >> 3;

    if (prep) attn_body32<1>(Qg, Kg, Vg, Kbf, Vtg, Og, sm16, b, qt5);
    else      attn_body32<0>(Qg, Kg, Vg, Kbf, Vtg, Og, sm16, b, qt5);
}

extern "C" void kernel_launch(void* const* d_in, const int* in_sizes, int n_in,
                              void* d_out, int out_size, void* d_ws, size_t ws_size,
                              hipStream_t stream) {
    const float* Q = (const float*)d_in[0];
    const float* K = (const float*)d_in[1];
    const float* V = (const float*)d_in[2];
    float* O = (float*)d_out;

    const size_t prep_bytes  = NELEM * 2 * 2;                          // 16,777,216
    const size_t split_bytes = prep_bytes + KSPLIT * NELEM * 4         // partials (50.3 MB)
                             + (size_t)KSPLIT * BATCH * SEQ * 4;       // L (0.4 MB)
    const bool prep  = (ws_size >= prep_bytes);
    const bool split = (ws_size >= split_bytes);

    unsigned short* Kbf = (unsigned short*)d_ws;
    unsigned short* Vtg = Kbf + NELEM;
    float* Opart = (float*)(Kbf + 2 * NELEM);
    float* Lpart = Opart + KSPLIT * NELEM;

    static int smem_cfged = 0;
    if (!smem_cfged) {
        (void)hipFuncSetAttribute((const void*)attn_fwd,
                                  hipFuncAttributeMaxDynamicSharedMemorySize, SMEM_BYTES);
        smem_cfged = 1;
    }

    if (prep)
        prep_all<<<dim3(2048 + BATCH * 128 * 4), 256, 0, stream>>>(K, V, Kbf, Vtg);

    if (split) {
        attn_split<<<dim3(BATCH * 32 * KSPLIT), 256, 0, stream>>>(Q, Kbf, Vtg, Opart, Lpart);
        merge_split<<<dim3(NELEM / (256 * 4)), 256, 0, stream>>>(Opart, Lpart, O);
    } else {
        attn_fwd<<<dim3(BATCH * (SEQ / 64)), 256, SMEM_BYTES, stream>>>(Q, K, V, Kbf, Vtg, O, prep ? 1 : 0);
    }
}

// Round 8
// 182.421 us; speedup vs baseline: 1.6329x; 1.0263x over previous
//
#include <hip/hip_runtime.h>

typedef __bf16 bf16x8 __attribute__((ext_vector_type(8)));
typedef float f32x4 __attribute__((ext_vector_type(4)));
typedef float f32x16 __attribute__((ext_vector_type(16)));
typedef unsigned short ushort8 __attribute__((ext_vector_type(8)));
typedef unsigned int uint4v __attribute__((ext_vector_type(4)));

#define BATCH 8
#define SEQ 4096
#define DH 128
#define NELEM 4194304ull     // BATCH*SEQ*DH
#define KSPLIT 2             // 2 planes x 2048 keys
#define NT 64                // 32-key steps per plane
#define SC (0.08838834764831845f * 1.4426950408889634f)

// ---- legacy dynamic-LDS map (u16 units), proven R3 path ----
#define OFF_V 16384
#define SMEM_BYTES 75776
// ---- split kernel dynamic LDS: 4-buf ring, K bufs [0..16383], V bufs [16384..32767] u16
#define SMEM_SPLIT 65536

__device__ __forceinline__ unsigned short f2bf(float x) {
    unsigned int u = __builtin_bit_cast(unsigned int, x);
    u = (u + 0x7FFFu + ((u >> 16) & 1u)) >> 16;
    return (unsigned short)u;
}
__device__ __forceinline__ ushort8 cvt8(const float* __restrict__ p) {
    f32x4 a = *(const f32x4*)p;
    f32x4 b = *(const f32x4*)(p + 4);
    ushort8 r;
    r[0] = f2bf(a[0]); r[1] = f2bf(a[1]); r[2] = f2bf(a[2]); r[3] = f2bf(a[3]);
    r[4] = f2bf(b[0]); r[5] = f2bf(b[1]); r[6] = f2bf(b[2]); r[7] = f2bf(b[3]);
    return r;
}
__device__ __forceinline__ ushort8 cvt8s(const float* __restrict__ p, float sc) {
    f32x4 a = *(const f32x4*)p;
    f32x4 b = *(const f32x4*)(p + 4);
    ushort8 r;
    r[0] = f2bf(a[0] * sc); r[1] = f2bf(a[1] * sc); r[2] = f2bf(a[2] * sc); r[3] = f2bf(a[3] * sc);
    r[4] = f2bf(b[0] * sc); r[5] = f2bf(b[1] * sc); r[6] = f2bf(b[2] * sc); r[7] = f2bf(b[3] * sc);
    return r;
}
__device__ __forceinline__ bf16x8 ldb(const unsigned short* p) {
    return __builtin_bit_cast(bf16x8, *(const ushort8*)p);
}
__device__ __forceinline__ void gll16(const void* src, void* dst) {
    __builtin_amdgcn_global_load_lds((const __attribute__((address_space(1))) unsigned int*)src,
                                     (__attribute__((address_space(3))) unsigned int*)dst, 16, 0, 0);
}
__device__ __forceinline__ unsigned int cvtpk(float lo, float hi) {
    unsigned int r;
    asm("v_cvt_pk_bf16_f32 %0, %1, %2" : "=v"(r) : "v"(lo), "v"(hi));
    return r;
}
__device__ __forceinline__ bf16x8 frag4(unsigned int a, unsigned int b,
                                        unsigned int c, unsigned int d) {
    uint4v u; u[0] = a; u[1] = b; u[2] = c; u[3] = d;
    return __builtin_bit_cast(bf16x8, u);
}

// ---------------- merged prep kernel: K->bf16, V->bf16 transposed ----------------
__global__ __launch_bounds__(256) void prep_all(const float* __restrict__ Kg,
                                                const float* __restrict__ Vg,
                                                unsigned short* __restrict__ Kbf,
                                                unsigned short* __restrict__ Vtg) {
    __shared__ float T[32 * 36];
    if (blockIdx.x < 2048) {
        size_t i = ((size_t)blockIdx.x * 256 + threadIdx.x) * 8;
        *(ushort8*)(Kbf + i) = cvt8(Kg + i);
        return;
    }
    const int bid = blockIdx.x - 2048;
    const int b  = bid >> 9;
    const int kt = (bid >> 2) & 127;
    const int dt = bid & 3;
    const int tid = threadIdx.x;
    {
        int r = tid >> 3, c4 = (tid & 7) * 4;
        f32x4 v = *(const f32x4*)(Vg + ((size_t)b * SEQ + kt * 32 + r) * DH + dt * 32 + c4);
        *(f32x4*)(&T[r * 36 + c4]) = v;
    }
    __syncthreads();
    {
        int rd = tid >> 3, kc4 = (tid & 7) * 4;
        unsigned long long w = 0;
#pragma unroll
        for (int j = 0; j < 4; ++j)
            w |= (unsigned long long)f2bf(T[(kc4 + j) * 36 + rd]) << (16 * j);
        *(unsigned long long*)(Vtg + ((size_t)b * DH + dt * 32 + rd) * SEQ + kt * 32 + kc4) = w;
    }
}

// ==================================================================================
// SPLIT-K, residency-exact: 512 blocks (8b x 32qt x 2ks) = 2 blocks/CU, single round
// (reg alloc granule rounds ~200 regs to 256 -> 2 waves/SIMD is the quantized ceiling).
// T15 2-tile pipeline: QK(t) || softmax+PV(t-1). 4-buffer LDS ring (64KB), 2-deep
// prefetch, one barrier + vmcnt(4)/step. VALU diet: Q pre-scaled by SC, zro C-operand,
// row-sum L via mfma(pf, ones).
// LDS map (u16): K[buf] at buf*4096 (32 key-rows x 256B, src-swz byte^=(row&7)<<4)
//                V[buf] at 16384+buf*4096 (128 d-rows x 64B, slot^=(row>>1)&3)
// ==================================================================================
__global__ __launch_bounds__(256, 2)
void attn_split(const float* __restrict__ Qg,
                const unsigned short* __restrict__ Kbf,
                const unsigned short* __restrict__ Vtg,
                float* __restrict__ Opart, float* __restrict__ Lpart)
{
    extern __shared__ __align__(16) unsigned char smem[];
    unsigned short* sm16 = (unsigned short*)smem;

    const int tid  = threadIdx.x;
    const int wv   = tid >> 6;
    const int lane = tid & 63;
    const int l32  = lane & 31;
    const int h    = lane >> 5;

    const int b  = blockIdx.x & 7;          // batch -> XCD slot (K/V L2 locality)
    const int rr = blockIdx.x >> 3;         // 0..63
    const int ks = rr & 1;
    const int qt = rr >> 1;                 // 0..31
    const int kb0 = ks * 2048;

    const int q0 = qt * 128 + wv * 32;
    const size_t qbase = (size_t)b * SEQ + q0;

    // Q as B-operand, PRE-SCALED by SC: B[k][n=q], n=l32 ; k = h*8+j per d-chunk c
    bf16x8 qf[8];
#pragma unroll
    for (int c = 0; c < 8; ++c)
        qf[c] = __builtin_bit_cast(bf16x8, cvt8s(Qg + (qbase + l32) * DH + c * 16 + h * 8, SC));

    const f32x16 zro = {0.f,0.f,0.f,0.f,0.f,0.f,0.f,0.f,0.f,0.f,0.f,0.f,0.f,0.f,0.f,0.f};
    f32x16 oacc[4];
#pragma unroll
    for (int dt = 0; dt < 4; ++dt) oacc[dt] = zro;
    f32x16 lacc = zro;                       // rowsum accumulator via mfma(pf, ones)
    ushort8 one_u;
#pragma unroll
    for (int j = 0; j < 8; ++j) one_u[j] = 0x3F80;   // bf16 1.0
    const bf16x8 ones8 = __builtin_bit_cast(bf16x8, one_u);

    const int swzK = (l32 & 7) << 4;

    // persistent staging source pointers (role by wave: wv<2 -> K halves, else V halves)
    const unsigned char* srcp[4];
    long sstr;
    if (wv < 2) {
        const unsigned short* Kb = Kbf + (size_t)b * SEQ * DH;
#pragma unroll
        for (int ch = 0; ch < 4; ++ch) {
            const int row  = wv * 16 + ch * 4 + (lane >> 4);
            const int colb = ((lane & 15) << 4) ^ ((row & 7) << 4);
            srcp[ch] = (const unsigned char*)(Kb + (size_t)(kb0 + row) * DH) + colb;
        }
        sstr = 32 * DH * 2;        // 8192 B per step
    } else {
        const unsigned short* Vb = Vtg + (size_t)b * DH * SEQ;
#pragma unroll
        for (int ch = 0; ch < 4; ++ch) {
            const int row  = (wv - 2) * 64 + ch * 16 + (lane >> 2);
            const int slot = (lane & 3) ^ ((row >> 1) & 3);
            srcp[ch] = (const unsigned char*)(Vb + (size_t)row * SEQ + kb0 + slot * 8);
        }
        sstr = 64;                 // 32 keys * 2 B per step
    }

#define STAGE(bufv)                                                                 \
    {                                                                               \
        unsigned short* bse = (wv < 2)                                              \
            ? sm16 + (bufv) * 4096 + wv * 2048                                      \
            : sm16 + 16384 + (bufv) * 4096 + (wv - 2) * 2048;                       \
        _Pragma("unroll")                                                           \
        for (int ch = 0; ch < 4; ++ch) {                                            \
            gll16(srcp[ch], bse + ch * 512);                                        \
            srcp[ch] += sstr;                                                       \
        }                                                                           \
    }

// QK phase for tile T: wait own tile-T loads (NW=4: tile T+1 stays in flight),
// barrier (block-wide visibility), 8 MFMA into CUR (zro C-operand, no acc-zeroing),
// then issue stage of tile T+2.
#define QK_PHASE(T, CUR, NW)                                                        \
    {                                                                               \
        asm volatile("s_waitcnt vmcnt(" #NW ")" ::: "memory");                      \
        __builtin_amdgcn_s_barrier();                                               \
        asm volatile("" ::: "memory");                                              \
        const unsigned char* Kbb_ = (const unsigned char*)(sm16 + ((T) & 3) * 4096);\
        __builtin_amdgcn_s_setprio(1);                                              \
        {                                                                           \
            bf16x8 kf_ = ldb((const unsigned short*)(Kbb_ + l32 * 256 + ((h * 16) ^ swzK))); \
            CUR = __builtin_amdgcn_mfma_f32_32x32x16_bf16(kf_, qf[0], zro, 0, 0, 0);\
        }                                                                           \
        _Pragma("unroll")                                                           \
        for (int c_ = 1; c_ < 8; ++c_) {                                            \
            bf16x8 kf_ = ldb((const unsigned short*)(Kbb_ + l32 * 256 + ((c_ * 32 + h * 16) ^ swzK))); \
            CUR = __builtin_amdgcn_mfma_f32_32x32x16_bf16(kf_, qf[c_], CUR, 0, 0, 0);\
        }                                                                           \
        __builtin_amdgcn_s_setprio(0);                                              \
        if ((T) + 2 < NT) { STAGE(((T) + 2) & 3); }                                 \
    }

// softmax + PV for tile T (scores in PREV): p = exp2(S) (SC folded into Q),
// pack to bf16, half-swap, L-rowsum via mfma(pf, ones), then 8 PV MFMA.
#define SM_PV(T, PREV)                                                              \
    {                                                                               \
        unsigned int w_[8];                                                         \
        _Pragma("unroll")                                                           \
        for (int i_ = 0; i_ < 8; ++i_) {                                            \
            float pa_ = exp2f(PREV[2 * i_]);                                        \
            float pb_ = exp2f(PREV[2 * i_ + 1]);                                    \
            w_[i_] = cvtpk(pa_, pb_);                                               \
        }                                                                           \
        unsigned int t0_ = __shfl_xor(h ? w_[0] : w_[2], 32);                       \
        unsigned int t1_ = __shfl_xor(h ? w_[1] : w_[3], 32);                       \
        unsigned int t2_ = __shfl_xor(h ? w_[4] : w_[6], 32);                       \
        unsigned int t3_ = __shfl_xor(h ? w_[5] : w_[7], 32);                       \
        bf16x8 pf0_ = frag4(h ? t0_ : w_[0], h ? t1_ : w_[1], h ? w_[2] : t0_, h ? w_[3] : t1_); \
        bf16x8 pf1_ = frag4(h ? t2_ : w_[4], h ? t3_ : w_[5], h ? w_[6] : t2_, h ? w_[7] : t3_); \
        const unsigned short* Vt_ = sm16 + 16384 + ((T) & 3) * 4096;                \
        __builtin_amdgcn_s_setprio(1);                                              \
        lacc = __builtin_amdgcn_mfma_f32_32x32x16_bf16(pf0_, ones8, lacc, 0, 0, 0); \
        lacc = __builtin_amdgcn_mfma_f32_32x32x16_bf16(pf1_, ones8, lacc, 0, 0, 0); \
        _Pragma("unroll")                                                           \
        for (int dt_ = 0; dt_ < 4; ++dt_) {                                         \
            const int d_  = dt_ * 32 + l32;                                         \
            const int sw_ = (d_ >> 1) & 3;                                          \
            bf16x8 v0_ = ldb(Vt_ + d_ * 32 + ((h    ) ^ sw_) * 8);                  \
            bf16x8 v1_ = ldb(Vt_ + d_ * 32 + ((2 + h) ^ sw_) * 8);                  \
            oacc[dt_] = __builtin_amdgcn_mfma_f32_32x32x16_bf16(pf0_, v0_, oacc[dt_], 0, 0, 0); \
            oacc[dt_] = __builtin_amdgcn_mfma_f32_32x32x16_bf16(pf1_, v1_, oacc[dt_], 0, 0, 0); \
        }                                                                           \
        __builtin_amdgcn_s_setprio(0);                                              \
    }

    asm volatile("s_waitcnt vmcnt(0)" ::: "memory");   // Q loads drained
    STAGE(0);
    STAGE(1);

    f32x16 sA, sB;
    QK_PHASE(0, sA, 4)
    for (int t = 1; t < NT - 1; t += 2) {
        QK_PHASE(t, sB, 4)
        SM_PV(t - 1, sA)
        QK_PHASE(t + 1, sA, 4)
        SM_PV(t, sB)
    }
    QK_PHASE(NT - 1, sB, 0)
    SM_PV(NT - 2, sA)
    SM_PV(NT - 1, sB)
#undef STAGE
#undef QK_PHASE
#undef SM_PV

    // ---- write partials: numerator (f32) + rowsum L (lacc cols all equal)
    if (l32 == 0) {
#pragma unroll
        for (int r = 0; r < 16; ++r) {
            const int qr = (r & 3) + 8 * (r >> 2) + 4 * h;
            Lpart[(size_t)ks * (BATCH * SEQ) + (size_t)b * SEQ + q0 + qr] = lacc[r];
        }
    }
    float* Op = Opart + (size_t)ks * NELEM;
#pragma unroll
    for (int dt = 0; dt < 4; ++dt)
#pragma unroll
        for (int r = 0; r < 16; ++r) {
            const int qr = (r & 3) + 8 * (r >> 2) + 4 * h;
            Op[(qbase + qr) * DH + dt * 32 + l32] = oacc[dt][r];
        }
}

// merge the 2 ks-planes: O = (sum Op) / (sum L)
__global__ __launch_bounds__(256)
void merge_split(const float* __restrict__ Opart, const float* __restrict__ Lpart,
                 float* __restrict__ O)
{
    const size_t g  = (size_t)blockIdx.x * 256 + threadIdx.x;   // 1,048,576 threads
    const size_t i4 = g * 4;
    const size_t bq = i4 >> 7;                                  // b*SEQ + q
    float L = Lpart[bq] + Lpart[BATCH * SEQ + bq];
    const float inv = 1.0f / L;
    f32x4 a  = *(const f32x4*)&Opart[i4];
    f32x4 b1 = *(const f32x4*)&Opart[NELEM + i4];
#pragma unroll
    for (int j = 0; j < 4; ++j) a[j] = (a[j] + b1[j]) * inv;
    *(f32x4*)&O[i4] = a;
}

// ==================================================================================
// LEGACY PATH (proven R3, 124us): 512 blocks, 2 kh-streams in-block, LDS merge.
// Used when ws is too small for split-K partials.
// ==================================================================================
__device__ __forceinline__ void issue_stage(const unsigned short* __restrict__ Kbf,
                                            const unsigned short* __restrict__ Vtg,
                                            unsigned short* sm16, int b, int kh, int qh,
                                            int lane, int t)
{
    const int buf = t & 1;
    const int kb  = kh * 2048 + t * 32;
    const int rin = lane >> 4;
    const int sb  = (lane & 15) << 4;
    const unsigned short* Kb = Kbf + (size_t)b * SEQ * DH;
#pragma unroll
    for (int ch = 0; ch < 4; ++ch) {
        const int row = qh * 16 + ch * 4 + rin;
        const unsigned char* src =
            (const unsigned char*)(Kb + (size_t)(kb + row) * DH) + (sb ^ ((row & 7) << 4));
        unsigned short* dst = sm16 + (kh * 2 + buf) * 4096 + (qh * 16 + ch * 4) * 128;
        gll16(src, dst);
    }
    const unsigned short* Vb = Vtg + (size_t)b * DH * SEQ;
    const int vr = lane >> 2, vs = lane & 3;
#pragma unroll
    for (int ch = 0; ch < 4; ++ch) {
        const int row = qh * 64 + ch * 16 + vr;
        const int slot = vs ^ ((row >> 1) & 3);
        const unsigned short* src = Vb + (size_t)row * SEQ + kb + slot * 8;
        unsigned short* dst = sm16 + OFF_V + (kh * 2 + buf) * 4096 + (qh * 64 + ch * 16) * 32;
        gll16(src, dst);
    }
}

__device__ __forceinline__ void stage_fallback(const float* __restrict__ Kg,
                                               const float* __restrict__ Vg,
                                               unsigned short* sm16, int b, int tid, int t)
{
    const int buf = t & 1;
#pragma unroll
    for (int s = 0; s < 2; ++s) {
        const int kb = s * 2048 + t * 32;
        {
            int r = tid >> 3, cg = tid & 7;
            const float* sp = Kg + ((size_t)b * SEQ + kb + r) * DH + cg * 16;
            ushort8 lo = cvt8(sp), hi = cvt8(sp + 8);
            unsigned char* kd = (unsigned char*)(sm16 + (s * 2 + buf) * 4096) + r * 256;
            int sbb = cg * 32, m = (r & 7) << 4;
            *(ushort8*)(kd + (sbb ^ m))        = lo;
            *(ushort8*)(kd + ((sbb + 16) ^ m)) = hi;
        }
        {
            int d = tid >> 1, half = tid & 1, sw = (d >> 1) & 3;
            ushort8 a, c;
#pragma unroll
            for (int j = 0; j < 8; ++j) {
                a[j] = f2bf(Vg[((size_t)b * SEQ + kb + half * 16 + j) * DH + d]);
                c[j] = f2bf(Vg[((size_t)b * SEQ + kb + half * 16 + 8 + j) * DH + d]);
            }
            unsigned short* vd = sm16 + OFF_V + (s * 2 + buf) * 4096 + d * 32;
            *(ushort8*)(vd + ((half * 2    ) ^ sw) * 8) = a;
            *(ushort8*)(vd + ((half * 2 + 1) ^ sw) * 8) = c;
        }
    }
}

template<int PREP>
__device__ __forceinline__ void attn_body32(
    const float* __restrict__ Qg, const float* __restrict__ Kg,
    const float* __restrict__ Vg,
    const unsigned short* __restrict__ Kbf, const unsigned short* __restrict__ Vtg,
    float* __restrict__ Og, unsigned short* sm16, int b, int qt5)
{
    const int tid  = threadIdx.x;
    const int wv   = tid >> 6;
    const int lane = tid & 63;
    const int l32  = lane & 31;
    const int h    = lane >> 5;
    const int qh = wv & 1;
    const int kh = wv >> 1;

    const size_t qbase = (size_t)b * SEQ + (size_t)qt5 * 64 + qh * 32;

    bf16x8 qf[8];
#pragma unroll
    for (int c = 0; c < 8; ++c)
        qf[c] = __builtin_bit_cast(bf16x8, cvt8(Qg + (qbase + l32) * DH + c * 16 + h * 8));

    f32x16 oacc[4];
#pragma unroll
    for (int dt = 0; dt < 4; ++dt)
#pragma unroll
        for (int r = 0; r < 16; ++r) oacc[dt][r] = 0.f;
    float lpA = 0.f, lpB = 0.f;
    const int swzK = (l32 & 7) << 4;

    asm volatile("s_waitcnt vmcnt(0)" ::: "memory");
    if (PREP) issue_stage(Kbf, Vtg, sm16, b, kh, qh, lane, 0);
    else      stage_fallback(Kg, Vg, sm16, b, tid, 0);

    for (int t = 0; t < 64; ++t) {
        __builtin_amdgcn_s_barrier();
        asm volatile("" ::: "memory");
        if (PREP) {
            if (t < 63) {
                issue_stage(Kbf, Vtg, sm16, b, kh, qh, lane, t + 1);
                asm volatile("s_waitcnt vmcnt(8)" ::: "memory");
            } else {
                asm volatile("s_waitcnt vmcnt(0)" ::: "memory");
            }
        } else {
            if (t < 63) stage_fallback(Kg, Vg, sm16, b, tid, t + 1);
            asm volatile("s_waitcnt vmcnt(0) lgkmcnt(0)" ::: "memory");
        }
        __builtin_amdgcn_s_barrier();
        asm volatile("" ::: "memory");

        const unsigned char*  Kbb = (const unsigned char*)(sm16 + (kh * 2 + (t & 1)) * 4096);
        const unsigned short* Vt  = sm16 + OFF_V + (kh * 2 + (t & 1)) * 4096;

        __builtin_amdgcn_s_setprio(1);
        f32x16 s;
#pragma unroll
        for (int r = 0; r < 16; ++r) s[r] = 0.f;
#pragma unroll
        for (int c = 0; c < 8; ++c) {
            bf16x8 kf = ldb((const unsigned short*)(Kbb + l32 * 256 + ((c * 32 + h * 16) ^ swzK)));
            s = __builtin_amdgcn_mfma_f32_32x32x16_bf16(kf, qf[c], s, 0, 0, 0);
        }
        __builtin_amdgcn_s_setprio(0);

        unsigned int w[8];
#pragma unroll
        for (int i = 0; i < 8; ++i) {
            float pa = exp2f(s[2 * i]     * SC);
            float pb = exp2f(s[2 * i + 1] * SC);
            lpA += pa; lpB += pb;
            w[i] = cvtpk(pa, pb);
        }
        unsigned int t0 = __shfl_xor(h ? w[0] : w[2], 32);
        unsigned int t1 = __shfl_xor(h ? w[1] : w[3], 32);
        unsigned int t2 = __shfl_xor(h ? w[4] : w[6], 32);
        unsigned int t3 = __shfl_xor(h ? w[5] : w[7], 32);
        bf16x8 pf0 = frag4(h ? t0 : w[0], h ? t1 : w[1], h ? w[2] : t0, h ? w[3] : t1);
        bf16x8 pf1 = frag4(h ? t2 : w[4], h ? t3 : w[5], h ? w[6] : t2, h ? w[7] : t3);

        __builtin_amdgcn_s_setprio(1);
#pragma unroll
        for (int dt = 0; dt < 4; ++dt) {
            const int d  = dt * 32 + l32;
            const int sw = (d >> 1) & 3;
            bf16x8 v0 = ldb(Vt + d * 32 + ((h    ) ^ sw) * 8);
            bf16x8 v1 = ldb(Vt + d * 32 + ((2 + h) ^ sw) * 8);
            oacc[dt] = __builtin_amdgcn_mfma_f32_32x32x16_bf16(pf0, v0, oacc[dt], 0, 0, 0);
            oacc[dt] = __builtin_amdgcn_mfma_f32_32x32x16_bf16(pf1, v1, oacc[dt], 0, 0, 0);
        }
        __builtin_amdgcn_s_setprio(0);
    }

    float lp2 = lpA + lpB;
    lp2 += __shfl_xor(lp2, 32);
    float* Om = (float*)sm16;
    float* lb = (float*)((char*)sm16 + 65536);
    __syncthreads();
    if (h == 0) lb[kh * 64 + qh * 32 + l32] = lp2;
    if (kh == 1) {
#pragma unroll
        for (int dt = 0; dt < 4; ++dt)
#pragma unroll
            for (int r = 0; r < 16; ++r) {
                const int qr = (r & 3) + 8 * (r >> 2) + 4 * h;
                Om[(qh * 32 + qr) * 128 + dt * 32 + l32] = oacc[dt][r];
            }
    }
    __syncthreads();
    if (kh == 0) {
        float invr[16];
#pragma unroll
        for (int r = 0; r < 16; ++r) {
            const int qr = (r & 3) + 8 * (r >> 2) + 4 * h;
            invr[r] = 1.0f / (lb[qh * 32 + qr] + lb[64 + qh * 32 + qr]);
        }
#pragma unroll
        for (int dt = 0; dt < 4; ++dt)
#pragma unroll
            for (int r = 0; r < 16; ++r) {
                const int qr = (r & 3) + 8 * (r >> 2) + 4 * h;
                Og[(qbase + qr) * DH + dt * 32 + l32] =
                    (oacc[dt][r] + Om[(qh * 32 + qr) * 128 + dt * 32 + l32]) * invr[r];
            }
    }
}

__global__ __launch_bounds__(256, 2)
void attn_fwd(const float* __restrict__ Qg, const float* __restrict__ Kg,
              const float* __restrict__ Vg,
              const unsigned short* __restrict__ Kbf,
              const unsigned short* __restrict__ Vtg,
              float* __restrict__ Og, int prep)
{
    extern __shared__ __align__(16) unsigned char smem[];
    unsigned short* sm16 = (unsigned short*)smem;

    const int b   = blockIdx.x & 7;
    const int qt5 = blockIdx.x >> 3;

    if (prep) attn_body32<1>(Qg, Kg, Vg, Kbf, Vtg, Og, sm16, b, qt5);
    else      attn_body32<0>(Qg, Kg, Vg, Kbf, Vtg, Og, sm16, b, qt5);
}

extern "C" void kernel_launch(void* const* d_in, const int* in_sizes, int n_in,
                              void* d_out, int out_size, void* d_ws, size_t ws_size,
                              hipStream_t stream) {
    const float* Q = (const float*)d_in[0];
    const float* K = (const float*)d_in[1];
    const float* V = (const float*)d_in[2];
    float* O = (float*)d_out;

    const size_t prep_bytes  = NELEM * 2 * 2;                          // 16,777,216
    const size_t split_bytes = prep_bytes + KSPLIT * NELEM * 4         // partials (33.6 MB)
                             + (size_t)KSPLIT * BATCH * SEQ * 4;       // L (0.26 MB)
    const bool prep  = (ws_size >= prep_bytes);
    const bool split = (ws_size >= split_bytes);

    unsigned short* Kbf = (unsigned short*)d_ws;
    unsigned short* Vtg = Kbf + NELEM;
    float* Opart = (float*)(Kbf + 2 * NELEM);
    float* Lpart = Opart + KSPLIT * NELEM;

    static int smem_cfged = 0;
    if (!smem_cfged) {
        (void)hipFuncSetAttribute((const void*)attn_fwd,
                                  hipFuncAttributeMaxDynamicSharedMemorySize, SMEM_BYTES);
        (void)hipFuncSetAttribute((const void*)attn_split,
                                  hipFuncAttributeMaxDynamicSharedMemorySize, SMEM_SPLIT);
        smem_cfged = 1;
    }

    if (prep)
        prep_all<<<dim3(2048 + BATCH * 128 * 4), 256, 0, stream>>>(K, V, Kbf, Vtg);

    if (split) {
        attn_split<<<dim3(BATCH * 32 * KSPLIT), 256, SMEM_SPLIT, stream>>>(Q, Kbf, Vtg, Opart, Lpart);
        merge_split<<<dim3(NELEM / (256 * 4)), 256, 0, stream>>>(Opart, Lpart, O);
    } else {
        attn_fwd<<<dim3(BATCH * (SEQ / 64)), 256, SMEM_BYTES, stream>>>(Q, K, V, Kbf, Vtg, O, prep ? 1 : 0);
    }
}